// Round 9
// baseline (79.266 us; speedup 1.0000x reference)
//
#include <hip/hip_runtime.h>
#include <math.h>

#define KPTS 133
#define FPS (KPTS * 3)            // 399 floats per sample
#define WPB 8                     // waves (= samples) per block, 512 threads
#define BLK_F4 ((WPB * FPS) / 4)  // 798 float4 per array per block (exact)

__device__ __forceinline__ float det3(float a0, float a1, float a2,
                                      float b0, float b1, float b2,
                                      float c0, float c1, float c2) {
    return a0 * (b1 * c2 - b2 * c1)
         - a1 * (b0 * c2 - b2 * c0)
         + a2 * (b0 * c1 - b1 * c0);
}

// Pipeline split (vs R2-R7 fused kernels): the per-sample Horn solve is
// embarrassingly parallel ACROSS THE GRID (65536 threads ~= 1 us total),
// instead of a 1-wave bubble behind block barriers or a 64-lane-redundant
// issue tax. K1/K3 keep the proven coalesced float4->LDS staging.

// ---------------- K1: moments ----------------
__global__ __launch_bounds__(512, 8) void moment_kernel(
    const float* __restrict__ outp,
    const float* __restrict__ tgtp,
    float* __restrict__ mom_g,        // (nsamp, 16)
    int nsamp)
{
    const int lane = threadIdx.x & 63;
    const int wid  = threadIdx.x >> 6;
    const int base = blockIdx.x * WPB;
    const int s    = base + wid;
    const bool valid = (s < nsamp);

    __shared__ __align__(16) float tl[WPB * FPS];
    __shared__ __align__(16) float ol[WPB * FPS];

    // stage: aligned float4 global -> LDS
    {
        const long blk_f4 = (long)base * FPS / 4;
        const long nfl    = (long)nsamp * FPS;
        const float4* tg4 = (const float4*)tgtp;
        const float4* og4 = (const float4*)outp;
        float4* tl4 = (float4*)tl;
        float4* ol4 = (float4*)ol;
        #pragma unroll
        for (int r = 0; r < 2; ++r) {
            const int i = (int)threadIdx.x + 512 * r;
            if (i < BLK_F4) {
                const long g4 = blk_f4 + i;
                if ((g4 + 1) * 4 <= nfl) {
                    tl4[i] = tg4[g4];
                    ol4[i] = og4[g4];
                } else {
                    #pragma unroll
                    for (int c = 0; c < 4; ++c) {
                        const long g = g4 * 4 + c;
                        float tv = 0.f, ov = 0.f;
                        if (g < nfl) { tv = tgtp[g]; ov = outp[g]; }
                        tl[i * 4 + c] = tv;
                        ol[i * 4 + c] = ov;
                    }
                }
            }
        }
    }
    __syncthreads();

    const float* tw = tl + wid * FPS;
    const float* ow = ol + wid * FPS;

    // red: [0..2]=sum_t, [3..5]=sum_o, [6..14]=sum t_a*o_b, [15]=sum t.t
    float red[16];
    #pragma unroll
    for (int i = 0; i < 16; ++i) red[i] = 0.0f;

    if (valid) {
        #pragma unroll
        for (int j = 0; j < 3; ++j) {
            const int k = lane + 64 * j;
            if (k < KPTS) {
                const float t0 = tw[3 * k + 0], t1 = tw[3 * k + 1], t2 = tw[3 * k + 2];
                const float o0 = ow[3 * k + 0], o1 = ow[3 * k + 1], o2 = ow[3 * k + 2];
                red[0]  += t0;      red[1]  += t1;      red[2]  += t2;
                red[3]  += o0;      red[4]  += o1;      red[5]  += o2;
                red[6]  += t0 * o0; red[7]  += t0 * o1; red[8]  += t0 * o2;
                red[9]  += t1 * o0; red[10] += t1 * o1; red[11] += t1 * o2;
                red[12] += t2 * o0; red[13] += t2 * o1; red[14] += t2 * o2;
                red[15] += t0 * t0 + t1 * t1 + t2 * t2;
            }
        }
    }

    // value-splitting butterfly: lane l ends with 64-lane sum of red[l & 15]
    float v8[8];
    {
        const bool b = (lane & 1);
        #pragma unroll
        for (int m = 0; m < 8; ++m) {
            const float snd = b ? red[2 * m] : red[2 * m + 1];
            const float rcv = __shfl_xor(snd, 1, 64);
            v8[m] = (b ? red[2 * m + 1] : red[2 * m]) + rcv;
        }
    }
    float v4_[4];
    {
        const bool b = ((lane >> 1) & 1);
        #pragma unroll
        for (int m = 0; m < 4; ++m) {
            const float snd = b ? v8[2 * m] : v8[2 * m + 1];
            const float rcv = __shfl_xor(snd, 2, 64);
            v4_[m] = (b ? v8[2 * m + 1] : v8[2 * m]) + rcv;
        }
    }
    float v2_[2];
    {
        const bool b = ((lane >> 2) & 1);
        #pragma unroll
        for (int m = 0; m < 2; ++m) {
            const float snd = b ? v4_[2 * m] : v4_[2 * m + 1];
            const float rcv = __shfl_xor(snd, 4, 64);
            v2_[m] = (b ? v4_[2 * m + 1] : v4_[2 * m]) + rcv;
        }
    }
    float v1;
    {
        const bool b = ((lane >> 3) & 1);
        const float snd = b ? v2_[0] : v2_[1];
        const float rcv = __shfl_xor(snd, 8, 64);
        v1 = (b ? v2_[1] : v2_[0]) + rcv;
    }
    v1 += __shfl_xor(v1, 16, 64);
    v1 += __shfl_xor(v1, 32, 64);

    if (valid && lane < 16) mom_g[(size_t)s * 16 + lane] = v1;
}

// ---------------- K2: per-sample Horn solve (1 thread = 1 sample) ----------------
__global__ __launch_bounds__(256) void solve_kernel(
    float* __restrict__ mom_g,   // in: 16 moments; out (in-place): sR(9), t(3)
    int nsamp)
{
    const int s = blockIdx.x * 256 + threadIdx.x;
    if (s >= nsamp) return;

    float* mp = mom_g + (size_t)s * 16;
    float m_[16];
    {
        const float4* m4 = (const float4*)mp;
        const float4 A = m4[0], B = m4[1], C = m4[2], D = m4[3];
        m_[0]=A.x; m_[1]=A.y; m_[2]=A.z; m_[3]=A.w;
        m_[4]=B.x; m_[5]=B.y; m_[6]=B.z; m_[7]=B.w;
        m_[8]=C.x; m_[9]=C.y; m_[10]=C.z; m_[11]=C.w;
        m_[12]=D.x; m_[13]=D.y; m_[14]=D.z; m_[15]=D.w;
    }

    const float invK = 1.0f / (float)KPTS;
    const float mu1x = m_[0] * invK, mu1y = m_[1] * invK, mu1z = m_[2] * invK;
    const float mu2x = m_[3] * invK, mu2y = m_[4] * invK, mu2z = m_[5] * invK;

    const float Sxx = m_[6]  - m_[0] * m_[3] * invK;
    const float Sxy = m_[7]  - m_[0] * m_[4] * invK;
    const float Sxz = m_[8]  - m_[0] * m_[5] * invK;
    const float Syx = m_[9]  - m_[1] * m_[3] * invK;
    const float Syy = m_[10] - m_[1] * m_[4] * invK;
    const float Syz = m_[11] - m_[1] * m_[5] * invK;
    const float Szx = m_[12] - m_[2] * m_[3] * invK;
    const float Szy = m_[13] - m_[2] * m_[4] * invK;
    const float Szz = m_[14] - m_[2] * m_[5] * invK;
    const float var1 = m_[15] - (m_[0] * m_[0] + m_[1] * m_[1] + m_[2] * m_[2]) * invK;

    const float N00 = Sxx + Syy + Szz;
    const float N01 = Syz - Szy, N02 = Szx - Sxz, N03 = Sxy - Syx;
    const float N11 = Sxx - Syy - Szz, N12 = Sxy + Syx, N13 = Szx + Sxz;
    const float N22 = -Sxx + Syy - Szz, N23 = Syz + Szy;
    const float N33 = -Sxx - Syy + Szz;

    const float trKtK = Sxx * Sxx + Sxy * Sxy + Sxz * Sxz
                      + Syx * Syx + Syy * Syy + Syz * Syz
                      + Szx * Szx + Szy * Szy + Szz * Szz;
    const float c2 = -2.0f * trKtK;
    const float detK = det3(Sxx, Sxy, Sxz, Syx, Syy, Syz, Szx, Szy, Szz);
    const float c1 = -8.0f * detK;
    const float c0 =
          N00 * det3(N11, N12, N13, N12, N22, N23, N13, N23, N33)
        - N01 * det3(N01, N12, N13, N02, N22, N23, N03, N23, N33)
        + N02 * det3(N01, N11, N13, N02, N12, N23, N03, N13, N33)
        - N03 * det3(N01, N11, N12, N02, N12, N22, N03, N13, N23);

    float lam = sqrtf(fmaxf(3.0f * trKtK, 0.0f));
    #pragma unroll
    for (int it = 0; it < 14; ++it) {
        const float l2 = lam * lam;
        const float P  = (l2 + c2) * l2 + c1 * lam + c0;
        const float Pp = (4.0f * l2 + 2.0f * c2) * lam + c1;
        lam -= P / Pp;
    }

    const float M00 = N00 - lam, M11 = N11 - lam, M22 = N22 - lam, M33 = N33 - lam;
    const float a0 =  det3(M11, N12, N13, N12, M22, N23, N13, N23, M33);
    const float a1 = -det3(N01, N12, N13, N02, M22, N23, N03, N23, M33);
    const float a2 =  det3(N01, M11, N13, N02, N12, N23, N03, N13, M33);
    const float a3 = -det3(N01, M11, N12, N02, N12, M22, N03, N13, N23);
    const float b0 = -det3(N01, N02, N03, N12, M22, N23, N13, N23, M33);
    const float b1 =  det3(M00, N02, N03, N02, M22, N23, N03, N23, M33);
    const float b2 = -det3(M00, N01, N03, N02, N12, N23, N03, N13, M33);
    const float b3 =  det3(M00, N01, N02, N02, N12, M22, N03, N13, N23);
    const float na = a0 * a0 + a1 * a1 + a2 * a2 + a3 * a3;
    const float nb = b0 * b0 + b1 * b1 + b2 * b2 + b3 * b3;
    const bool pa_ = (na >= nb);
    float qw = pa_ ? a0 : b0;
    float qx = pa_ ? a1 : b1;
    float qy = pa_ ? a2 : b2;
    float qz = pa_ ? a3 : b3;
    const float qn = rsqrtf(fmaxf(qw * qw + qx * qx + qy * qy + qz * qz, 1e-30f));
    qw *= qn; qx *= qn; qy *= qn; qz *= qn;

    const float R00 = 1.0f - 2.0f * (qy * qy + qz * qz);
    const float R01 = 2.0f * (qx * qy - qw * qz);
    const float R02 = 2.0f * (qx * qz + qw * qy);
    const float R10 = 2.0f * (qx * qy + qw * qz);
    const float R11 = 1.0f - 2.0f * (qx * qx + qz * qz);
    const float R12 = 2.0f * (qy * qz - qw * qx);
    const float R20 = 2.0f * (qx * qz - qw * qy);
    const float R21 = 2.0f * (qy * qz + qw * qx);
    const float R22 = 1.0f - 2.0f * (qx * qx + qy * qy);

    const float trRK = R00 * Sxx + R01 * Syx + R02 * Szx
                     + R10 * Sxy + R11 * Syy + R12 * Szy
                     + R20 * Sxz + R21 * Syz + R22 * Szz;
    const float scale = trRK / var1;

    const float tx = mu2x - scale * (R00 * mu1x + R01 * mu1y + R02 * mu1z);
    const float ty = mu2y - scale * (R10 * mu1x + R11 * mu1y + R12 * mu1z);
    const float tz = mu2z - scale * (R20 * mu1x + R21 * mu1y + R22 * mu1z);

    // in-place params: sR(9), t(3) over slots 0..11
    float4* p4 = (float4*)mp;
    float4 P0, P1, P2;
    P0.x = scale * R00; P0.y = scale * R01; P0.z = scale * R02; P0.w = scale * R10;
    P1.x = scale * R11; P1.y = scale * R12; P1.z = scale * R20; P1.w = scale * R21;
    P2.x = scale * R22; P2.y = tx; P2.z = ty; P2.w = tz;
    p4[0] = P0; p4[1] = P1; p4[2] = P2;
}

// ---------------- K3: residual norms ----------------
__global__ __launch_bounds__(512, 8) void resid_kernel(
    const float* __restrict__ outp,
    const float* __restrict__ tgtp,
    const float* __restrict__ prm_g,   // (nsamp, 16): sR(9), t(3)
    float* __restrict__ block_sums,
    int nsamp)
{
    const int lane = threadIdx.x & 63;
    const int wid  = threadIdx.x >> 6;
    const int base = blockIdx.x * WPB;
    const int s    = base + wid;
    const bool valid = (s < nsamp);

    __shared__ __align__(16) float tl[WPB * FPS];
    __shared__ __align__(16) float ol[WPB * FPS];
    __shared__ float shs[WPB];

    {
        const long blk_f4 = (long)base * FPS / 4;
        const long nfl    = (long)nsamp * FPS;
        const float4* tg4 = (const float4*)tgtp;
        const float4* og4 = (const float4*)outp;
        float4* tl4 = (float4*)tl;
        float4* ol4 = (float4*)ol;
        #pragma unroll
        for (int r = 0; r < 2; ++r) {
            const int i = (int)threadIdx.x + 512 * r;
            if (i < BLK_F4) {
                const long g4 = blk_f4 + i;
                if ((g4 + 1) * 4 <= nfl) {
                    tl4[i] = tg4[g4];
                    ol4[i] = og4[g4];
                } else {
                    #pragma unroll
                    for (int c = 0; c < 4; ++c) {
                        const long g = g4 * 4 + c;
                        float tv = 0.f, ov = 0.f;
                        if (g < nfl) { tv = tgtp[g]; ov = outp[g]; }
                        tl[i * 4 + c] = tv;
                        ol[i * 4 + c] = ov;
                    }
                }
            }
        }
    }

    // params: wave-uniform float4 loads (lower to scalar loads)
    float sR00 = 0, sR01 = 0, sR02 = 0, sR10 = 0, sR11 = 0, sR12 = 0;
    float sR20 = 0, sR21 = 0, sR22 = 0, tx = 0, ty = 0, tz = 0;
    if (valid) {
        const float4* pp = (const float4*)(prm_g + (size_t)s * 16);
        const float4 P0 = pp[0], P1 = pp[1], P2 = pp[2];
        sR00 = P0.x; sR01 = P0.y; sR02 = P0.z; sR10 = P0.w;
        sR11 = P1.x; sR12 = P1.y; sR20 = P1.z; sR21 = P1.w;
        sR22 = P2.x; tx = P2.y; ty = P2.z; tz = P2.w;
    }
    __syncthreads();

    const float* tw = tl + wid * FPS;
    const float* ow = ol + wid * FPS;

    float rsum = 0.0f;
    if (valid) {
        #pragma unroll
        for (int j = 0; j < 3; ++j) {
            const int k = lane + 64 * j;
            if (k < KPTS) {
                const float t0 = tw[3 * k + 0], t1 = tw[3 * k + 1], t2 = tw[3 * k + 2];
                const float o0 = ow[3 * k + 0], o1 = ow[3 * k + 1], o2 = ow[3 * k + 2];
                const float ax = sR00 * t0 + sR01 * t1 + sR02 * t2 + tx;
                const float ay = sR10 * t0 + sR11 * t1 + sR12 * t2 + ty;
                const float az = sR20 * t0 + sR21 * t1 + sR22 * t2 + tz;
                const float dx = o0 - ax;
                const float dy = o1 - ay;
                const float dz = o2 - az;
                rsum += sqrtf(dx * dx + dy * dy + dz * dz);
            }
        }
    }
    #pragma unroll
    for (int off = 32; off >= 1; off >>= 1)
        rsum += __shfl_xor(rsum, off, 64);

    if (lane == 0) shs[wid] = rsum;
    __syncthreads();
    if (threadIdx.x == 0) {
        float b = 0.0f;
        #pragma unroll
        for (int i = 0; i < WPB; ++i) b += shs[i];
        block_sums[blockIdx.x] = b;
    }
}

// ---------------- K4: deterministic final reduce (4-way ILP) ----------------
__global__ __launch_bounds__(256) void pa_reduce_kernel(
    const float* __restrict__ block_sums, int n,
    float* __restrict__ out, float inv_total)
{
    __shared__ float sh[4];
    float a0 = 0.f, a1 = 0.f, a2 = 0.f, a3 = 0.f;
    for (int i = (int)threadIdx.x * 4; i < n; i += 1024) {
        if (i + 0 < n) a0 += block_sums[i + 0];
        if (i + 1 < n) a1 += block_sums[i + 1];
        if (i + 2 < n) a2 += block_sums[i + 2];
        if (i + 3 < n) a3 += block_sums[i + 3];
    }
    float v = (a0 + a1) + (a2 + a3);
    #pragma unroll
    for (int off = 32; off >= 1; off >>= 1) v += __shfl_xor(v, off, 64);
    const int lane = threadIdx.x & 63;
    const int wid  = threadIdx.x >> 6;
    if (lane == 0) sh[wid] = v;
    __syncthreads();
    if (threadIdx.x == 0) out[0] = (sh[0] + sh[1] + sh[2] + sh[3]) * inv_total;
}

extern "C" void kernel_launch(void* const* d_in, const int* in_sizes, int n_in,
                              void* d_out, int out_size, void* d_ws, size_t ws_size,
                              hipStream_t stream) {
    const float* outp = (const float*)d_in[0];   // "output"
    const float* tgtp = (const float*)d_in[1];   // "target"
    const int nsamp   = in_sizes[0] / FPS;
    const int nblocks = (nsamp + WPB - 1) / WPB;

    float* mom      = (float*)d_ws;                       // nsamp*16 floats
    float* partials = mom + (size_t)nsamp * 16;           // nblocks floats

    moment_kernel<<<nblocks, 512, 0, stream>>>(outp, tgtp, mom, nsamp);
    solve_kernel<<<(nsamp + 255) / 256, 256, 0, stream>>>(mom, nsamp);
    resid_kernel<<<nblocks, 512, 0, stream>>>(outp, tgtp, mom, partials, nsamp);
    pa_reduce_kernel<<<1, 256, 0, stream>>>(
        partials, nblocks, (float*)d_out,
        1.0f / ((float)nsamp * (float)KPTS));
}

// Round 10
// 53.921 us; speedup vs baseline: 1.4700x; 1.4700x over previous
//
#include <hip/hip_runtime.h>
#include <math.h>

#define KPTS 133
#define FPS  (KPTS * 3)          // 399 floats per sample
#define SPB  16                  // samples per block
#define SPWV 4                   // samples per wave (16 lanes each)
#define BLK_F4 ((SPB * FPS) / 4) // 1596 float4 per array per block (exact)

// DPP quad_perm shuffles: VALU-only (no LDS pipe, no lgkmcnt latency)
#define DPP_XOR1(x) __int_as_float(__builtin_amdgcn_update_dpp(0, __float_as_int(x), 0xB1, 0xF, 0xF, true))
#define DPP_XOR2(x) __int_as_float(__builtin_amdgcn_update_dpp(0, __float_as_int(x), 0x4E, 0xF, 0xF, true))

__device__ __forceinline__ float det3(float a0, float a1, float a2,
                                      float b0, float b1, float b2,
                                      float c0, float c1, float c2) {
    return a0 * (b1 * c2 - b2 * c1)
         - a1 * (b0 * c2 - b2 * c0)
         + a2 * (b0 * c1 - b1 * c0);
}

// R10: 4 samples/wave (16 lanes each) -> every per-sample overhead /4 vs the
// wave-per-sample designs (R2/R6/R7/R9 all ~68us). One fused pass:
//   stage f4->LDS (linear, aligned) -> in-lane moments (8-9 pts/lane) ->
//   4-stage group butterfly (xor1/2 via DPP quad_perm = VALU; only xor4/8
//   on the LDS pipe) -> mom tile -> 16-lane block solve (34 inst/sample) ->
//   residuals from the LDS image (no 2nd global pass) -> group reduce (DPP).
// 256-thr blocks, 53KB LDS -> 3 blocks/CU so other blocks cover the solve
// window and barriers.
__global__ __launch_bounds__(256, 3) void pa_mpjpe_kernel(
    const float* __restrict__ outp,   // (N,K,3) output
    const float* __restrict__ tgtp,   // (N,K,3) target
    float* __restrict__ block_sums,
    int nsamp)
{
    const int tid  = threadIdx.x;
    const int lane = tid & 63;
    const int wid  = tid >> 6;
    const int l16  = lane & 15;
    const int s_l  = wid * SPWV + (lane >> 4);   // local sample 0..15
    const int s    = blockIdx.x * SPB + s_l;
    const bool valid = (s < nsamp);

    __shared__ __align__(16) float tl[SPB * FPS];   // 25536 B
    __shared__ __align__(16) float ol[SPB * FPS];   // 25536 B
    __shared__ float momT[SPB][17];                 // 16 moments/sample
    __shared__ float prm[SPB][13];                  // sR(9), t(3)
    __shared__ float shs[SPB];

    // ---- stage: aligned float4 global -> LDS (block region is 16B-aligned:
    //      16 samples * 1596 B = 25536 B, multiple of 16) ----
    {
        const long blk_f4 = (long)blockIdx.x * BLK_F4;
        const long nfl    = (long)nsamp * FPS;
        const float4* tg4 = (const float4*)tgtp;
        const float4* og4 = (const float4*)outp;
        float4* tl4 = (float4*)tl;
        float4* ol4 = (float4*)ol;
        #pragma unroll
        for (int r = 0; r < 7; ++r) {
            const int i = tid + 256 * r;
            if (i < BLK_F4) {
                const long g4 = blk_f4 + i;
                if ((g4 + 1) * 4 <= nfl) {
                    tl4[i] = tg4[g4];
                    ol4[i] = og4[g4];
                } else {
                    #pragma unroll
                    for (int c = 0; c < 4; ++c) {
                        const long g = g4 * 4 + c;
                        float tv = 0.f, ov = 0.f;
                        if (g < nfl) { tv = tgtp[g]; ov = outp[g]; }
                        tl[i * 4 + c] = tv;
                        ol[i * 4 + c] = ov;
                    }
                }
            }
        }
    }
    __syncthreads();

    const float* tw = tl + s_l * FPS;
    const float* ow = ol + s_l * FPS;

    // ---- moments: lane handles points l16 + 16k, k=0..7 (<=127, unguarded)
    //      plus tail p=128+l16 for l16<5 ----
    float red[16];
    #pragma unroll
    for (int i = 0; i < 16; ++i) red[i] = 0.0f;

#define PA_ACC(t0, t1, t2, o0, o1, o2)                                      \
    red[0]  += (t0);        red[1]  += (t1);        red[2]  += (t2);        \
    red[3]  += (o0);        red[4]  += (o1);        red[5]  += (o2);        \
    red[6]  += (t0) * (o0); red[7]  += (t0) * (o1); red[8]  += (t0) * (o2); \
    red[9]  += (t1) * (o0); red[10] += (t1) * (o1); red[11] += (t1) * (o2); \
    red[12] += (t2) * (o0); red[13] += (t2) * (o1); red[14] += (t2) * (o2); \
    red[15] += (t0) * (t0) + (t1) * (t1) + (t2) * (t2);

    #pragma unroll
    for (int k = 0; k < 8; ++k) {
        const int idx = 3 * (l16 + 16 * k);
        const float t0 = tw[idx + 0], t1 = tw[idx + 1], t2 = tw[idx + 2];
        const float o0 = ow[idx + 0], o1 = ow[idx + 1], o2 = ow[idx + 2];
        PA_ACC(t0, t1, t2, o0, o1, o2)
    }
    if (l16 < 5) {
        const int idx = 3 * (128 + l16);
        const float t0 = tw[idx + 0], t1 = tw[idx + 1], t2 = tw[idx + 2];
        const float o0 = ow[idx + 0], o1 = ow[idx + 1], o2 = ow[idx + 2];
        PA_ACC(t0, t1, t2, o0, o1, o2)
    }
#undef PA_ACC

    // ---- 4-stage value-splitting butterfly within 16-lane group ----
    // xor1/xor2 via DPP quad_perm (VALU); xor4/xor8 via shuffle.
    // Lane l ends holding the group sum of red[l & 15].
    float v8[8];
    {
        const bool b = (lane & 1);
        #pragma unroll
        for (int m = 0; m < 8; ++m) {
            const float snd = b ? red[2 * m] : red[2 * m + 1];
            const float rcv = DPP_XOR1(snd);
            v8[m] = (b ? red[2 * m + 1] : red[2 * m]) + rcv;
        }
    }
    float v4_[4];
    {
        const bool b = ((lane >> 1) & 1);
        #pragma unroll
        for (int m = 0; m < 4; ++m) {
            const float snd = b ? v8[2 * m] : v8[2 * m + 1];
            const float rcv = DPP_XOR2(snd);
            v4_[m] = (b ? v8[2 * m + 1] : v8[2 * m]) + rcv;
        }
    }
    float v2_[2];
    {
        const bool b = ((lane >> 2) & 1);
        #pragma unroll
        for (int m = 0; m < 2; ++m) {
            const float snd = b ? v4_[2 * m] : v4_[2 * m + 1];
            const float rcv = __shfl_xor(snd, 4, 64);
            v2_[m] = (b ? v4_[2 * m + 1] : v4_[2 * m]) + rcv;
        }
    }
    float v1;
    {
        const bool b = ((lane >> 3) & 1);
        const float snd = b ? v2_[0] : v2_[1];
        const float rcv = __shfl_xor(snd, 8, 64);
        v1 = (b ? v2_[1] : v2_[0]) + rcv;
    }

    momT[s_l][l16] = v1;
    __syncthreads();

    // ---- solve: wave 0, lanes 0..15, one sample each (550/16 insts/sample) ----
    if (wid == 0 && lane < SPB && (blockIdx.x * SPB + lane) < nsamp) {
        float m_[16];
        #pragma unroll
        for (int j = 0; j < 16; ++j) m_[j] = momT[lane][j];

        const float invK = 1.0f / (float)KPTS;
        const float mu1x = m_[0] * invK, mu1y = m_[1] * invK, mu1z = m_[2] * invK;
        const float mu2x = m_[3] * invK, mu2y = m_[4] * invK, mu2z = m_[5] * invK;

        const float Sxx = m_[6]  - m_[0] * m_[3] * invK;
        const float Sxy = m_[7]  - m_[0] * m_[4] * invK;
        const float Sxz = m_[8]  - m_[0] * m_[5] * invK;
        const float Syx = m_[9]  - m_[1] * m_[3] * invK;
        const float Syy = m_[10] - m_[1] * m_[4] * invK;
        const float Syz = m_[11] - m_[1] * m_[5] * invK;
        const float Szx = m_[12] - m_[2] * m_[3] * invK;
        const float Szy = m_[13] - m_[2] * m_[4] * invK;
        const float Szz = m_[14] - m_[2] * m_[5] * invK;
        const float var1 = m_[15] - (m_[0] * m_[0] + m_[1] * m_[1] + m_[2] * m_[2]) * invK;

        const float N00 = Sxx + Syy + Szz;
        const float N01 = Syz - Szy, N02 = Szx - Sxz, N03 = Sxy - Syx;
        const float N11 = Sxx - Syy - Szz, N12 = Sxy + Syx, N13 = Szx + Sxz;
        const float N22 = -Sxx + Syy - Szz, N23 = Syz + Szy;
        const float N33 = -Sxx - Syy + Szz;

        const float trKtK = Sxx * Sxx + Sxy * Sxy + Sxz * Sxz
                          + Syx * Syx + Syy * Syy + Syz * Syz
                          + Szx * Szx + Szy * Szy + Szz * Szz;
        const float c2 = -2.0f * trKtK;
        const float detK = det3(Sxx, Sxy, Sxz, Syx, Syy, Syz, Szx, Szy, Szz);
        const float c1 = -8.0f * detK;
        const float c0 =
              N00 * det3(N11, N12, N13, N12, N22, N23, N13, N23, N33)
            - N01 * det3(N01, N12, N13, N02, N22, N23, N03, N23, N33)
            + N02 * det3(N01, N11, N13, N02, N12, N23, N03, N13, N33)
            - N03 * det3(N01, N11, N12, N02, N12, N22, N03, N13, N23);

        float lam = sqrtf(fmaxf(3.0f * trKtK, 0.0f));
        #pragma unroll
        for (int it = 0; it < 14; ++it) {
            const float l2 = lam * lam;
            const float P  = (l2 + c2) * l2 + c1 * lam + c0;
            const float Pp = (4.0f * l2 + 2.0f * c2) * lam + c1;
            lam -= P / Pp;
        }

        const float M00 = N00 - lam, M11 = N11 - lam, M22 = N22 - lam, M33 = N33 - lam;
        const float a0 =  det3(M11, N12, N13, N12, M22, N23, N13, N23, M33);
        const float a1 = -det3(N01, N12, N13, N02, M22, N23, N03, N23, M33);
        const float a2 =  det3(N01, M11, N13, N02, N12, N23, N03, N13, M33);
        const float a3 = -det3(N01, M11, N12, N02, N12, M22, N03, N13, N23);
        const float b0 = -det3(N01, N02, N03, N12, M22, N23, N13, N23, M33);
        const float b1 =  det3(M00, N02, N03, N02, M22, N23, N03, N23, M33);
        const float b2 = -det3(M00, N01, N03, N02, N12, N23, N03, N13, M33);
        const float b3 =  det3(M00, N01, N02, N02, N12, M22, N03, N13, N23);
        const float na = a0 * a0 + a1 * a1 + a2 * a2 + a3 * a3;
        const float nb = b0 * b0 + b1 * b1 + b2 * b2 + b3 * b3;
        const bool pa_ = (na >= nb);
        float qw = pa_ ? a0 : b0;
        float qx = pa_ ? a1 : b1;
        float qy = pa_ ? a2 : b2;
        float qz = pa_ ? a3 : b3;
        const float qn = rsqrtf(fmaxf(qw * qw + qx * qx + qy * qy + qz * qz, 1e-30f));
        qw *= qn; qx *= qn; qy *= qn; qz *= qn;

        const float R00 = 1.0f - 2.0f * (qy * qy + qz * qz);
        const float R01 = 2.0f * (qx * qy - qw * qz);
        const float R02 = 2.0f * (qx * qz + qw * qy);
        const float R10 = 2.0f * (qx * qy + qw * qz);
        const float R11 = 1.0f - 2.0f * (qx * qx + qz * qz);
        const float R12 = 2.0f * (qy * qz - qw * qx);
        const float R20 = 2.0f * (qx * qz - qw * qy);
        const float R21 = 2.0f * (qy * qz + qw * qx);
        const float R22 = 1.0f - 2.0f * (qx * qx + qy * qy);

        const float trRK = R00 * Sxx + R01 * Syx + R02 * Szx
                         + R10 * Sxy + R11 * Syy + R12 * Szy
                         + R20 * Sxz + R21 * Syz + R22 * Szz;
        const float scale = trRK / var1;

        const float tx = mu2x - scale * (R00 * mu1x + R01 * mu1y + R02 * mu1z);
        const float ty = mu2y - scale * (R10 * mu1x + R11 * mu1y + R12 * mu1z);
        const float tz = mu2z - scale * (R20 * mu1x + R21 * mu1y + R22 * mu1z);

        prm[lane][0] = scale * R00; prm[lane][1] = scale * R01; prm[lane][2] = scale * R02;
        prm[lane][3] = scale * R10; prm[lane][4] = scale * R11; prm[lane][5] = scale * R12;
        prm[lane][6] = scale * R20; prm[lane][7] = scale * R21; prm[lane][8] = scale * R22;
        prm[lane][9] = tx; prm[lane][10] = ty; prm[lane][11] = tz;
    }
    __syncthreads();

    // ---- residuals from the LDS image (no second global pass) ----
    const float sR00 = prm[s_l][0], sR01 = prm[s_l][1], sR02 = prm[s_l][2];
    const float sR10 = prm[s_l][3], sR11 = prm[s_l][4], sR12 = prm[s_l][5];
    const float sR20 = prm[s_l][6], sR21 = prm[s_l][7], sR22 = prm[s_l][8];
    const float tx = prm[s_l][9], ty = prm[s_l][10], tz = prm[s_l][11];

    float rsum = 0.0f;
#define PA_RES(t0, t1, t2, o0, o1, o2)                                   \
    {                                                                    \
        const float ax = sR00 * (t0) + sR01 * (t1) + sR02 * (t2) + tx;   \
        const float ay = sR10 * (t0) + sR11 * (t1) + sR12 * (t2) + ty;   \
        const float az = sR20 * (t0) + sR21 * (t1) + sR22 * (t2) + tz;   \
        const float dx = (o0) - ax;                                      \
        const float dy = (o1) - ay;                                      \
        const float dz = (o2) - az;                                      \
        rsum += sqrtf(dx * dx + dy * dy + dz * dz);                      \
    }
    #pragma unroll
    for (int k = 0; k < 8; ++k) {
        const int idx = 3 * (l16 + 16 * k);
        const float t0 = tw[idx + 0], t1 = tw[idx + 1], t2 = tw[idx + 2];
        const float o0 = ow[idx + 0], o1 = ow[idx + 1], o2 = ow[idx + 2];
        PA_RES(t0, t1, t2, o0, o1, o2)
    }
    if (l16 < 5) {
        const int idx = 3 * (128 + l16);
        const float t0 = tw[idx + 0], t1 = tw[idx + 1], t2 = tw[idx + 2];
        const float o0 = ow[idx + 0], o1 = ow[idx + 1], o2 = ow[idx + 2];
        PA_RES(t0, t1, t2, o0, o1, o2)
    }
#undef PA_RES

    rsum = valid ? rsum : 0.0f;   // zero invalid samples (NaN-safe select)

    // 16-lane group sum: xor1/2 via DPP, xor4/8 via shuffle
    rsum += DPP_XOR1(rsum);
    rsum += DPP_XOR2(rsum);
    rsum += __shfl_xor(rsum, 4, 64);
    rsum += __shfl_xor(rsum, 8, 64);

    if (l16 == 0) shs[s_l] = rsum;
    __syncthreads();
    if (tid == 0) {
        float b = 0.0f;
        #pragma unroll
        for (int i = 0; i < SPB; ++i) b += shs[i];
        block_sums[blockIdx.x] = b;
    }
}

// Deterministic final reduction: one block, fixed summation order, 4-way ILP.
__global__ __launch_bounds__(256) void pa_reduce_kernel(
    const float* __restrict__ block_sums, int n,
    float* __restrict__ out, float inv_total)
{
    __shared__ float sh[4];
    float a0 = 0.f, a1 = 0.f, a2 = 0.f, a3 = 0.f;
    for (int i = (int)threadIdx.x * 4; i < n; i += 1024) {
        if (i + 0 < n) a0 += block_sums[i + 0];
        if (i + 1 < n) a1 += block_sums[i + 1];
        if (i + 2 < n) a2 += block_sums[i + 2];
        if (i + 3 < n) a3 += block_sums[i + 3];
    }
    float v = (a0 + a1) + (a2 + a3);
    #pragma unroll
    for (int off = 32; off >= 1; off >>= 1) v += __shfl_xor(v, off, 64);
    const int lane = threadIdx.x & 63;
    const int wid  = threadIdx.x >> 6;
    if (lane == 0) sh[wid] = v;
    __syncthreads();
    if (threadIdx.x == 0) out[0] = (sh[0] + sh[1] + sh[2] + sh[3]) * inv_total;
}

extern "C" void kernel_launch(void* const* d_in, const int* in_sizes, int n_in,
                              void* d_out, int out_size, void* d_ws, size_t ws_size,
                              hipStream_t stream) {
    const float* outp = (const float*)d_in[0];   // "output"
    const float* tgtp = (const float*)d_in[1];   // "target"
    const int nsamp   = in_sizes[0] / FPS;
    const int nblocks = (nsamp + SPB - 1) / SPB;

    float* bsums = (float*)d_ws;

    pa_mpjpe_kernel<<<nblocks, 256, 0, stream>>>(outp, tgtp, bsums, nsamp);
    pa_reduce_kernel<<<1, 256, 0, stream>>>(
        bsums, nblocks, (float*)d_out,
        1.0f / ((float)nsamp * (float)KPTS));
}

// Round 11
// 52.328 us; speedup vs baseline: 1.5148x; 1.0304x over previous
//
#include <hip/hip_runtime.h>
#include <math.h>

#define KPTS 133
#define FPS  (KPTS * 3)          // 399 floats per sample
#define SPB  16                  // samples per block
#define SPWV 4                   // samples per wave (16 lanes each)
#define BLK_F4 ((SPB * FPS) / 4) // 1596 float4 per array per block (exact)

// DPP quad_perm shuffles: VALU-only (no LDS pipe, no lgkmcnt latency)
#define DPP_XOR1(x) __int_as_float(__builtin_amdgcn_update_dpp(0, __float_as_int(x), 0xB1, 0xF, 0xF, true))
#define DPP_XOR2(x) __int_as_float(__builtin_amdgcn_update_dpp(0, __float_as_int(x), 0x4E, 0xF, 0xF, true))

__device__ __forceinline__ float2 f2(float a, float b) { return make_float2(a, b); }

__device__ __forceinline__ float det3(float a0, float a1, float a2,
                                      float b0, float b1, float b2,
                                      float c0, float c1, float c2) {
    return a0 * (b1 * c2 - b2 * c1)
         - a1 * (b0 * c2 - b2 * c0)
         + a2 * (b0 * c1 - b1 * c0);
}

// R11 = R10 structure (4 samples/wave, fused single pass, 16-lane solve) +
// packed-FP32 (v_pk_fma_f32 via float2 arithmetic) in the two hot loops:
// moments 18->9 ops/point, residual 17->13 ops/point.
__global__ __launch_bounds__(256, 3) void pa_mpjpe_kernel(
    const float* __restrict__ outp,   // (N,K,3) output
    const float* __restrict__ tgtp,   // (N,K,3) target
    float* __restrict__ block_sums,
    int nsamp)
{
    const int tid  = threadIdx.x;
    const int lane = tid & 63;
    const int wid  = tid >> 6;
    const int l16  = lane & 15;
    const int s_l  = wid * SPWV + (lane >> 4);   // local sample 0..15
    const int s    = blockIdx.x * SPB + s_l;
    const bool valid = (s < nsamp);

    __shared__ __align__(16) float tl[SPB * FPS];   // 25536 B
    __shared__ __align__(16) float ol[SPB * FPS];   // 25536 B
    __shared__ float momT[SPB][17];
    __shared__ float prm[SPB][13];
    __shared__ float shs[SPB];

    // ---- stage: aligned float4 global -> LDS ----
    {
        const long blk_f4 = (long)blockIdx.x * BLK_F4;
        const long nfl    = (long)nsamp * FPS;
        const float4* tg4 = (const float4*)tgtp;
        const float4* og4 = (const float4*)outp;
        float4* tl4 = (float4*)tl;
        float4* ol4 = (float4*)ol;
        #pragma unroll
        for (int r = 0; r < 7; ++r) {
            const int i = tid + 256 * r;
            if (i < BLK_F4) {
                const long g4 = blk_f4 + i;
                if ((g4 + 1) * 4 <= nfl) {
                    tl4[i] = tg4[g4];
                    ol4[i] = og4[g4];
                } else {
                    #pragma unroll
                    for (int c = 0; c < 4; ++c) {
                        const long g = g4 * 4 + c;
                        float tv = 0.f, ov = 0.f;
                        if (g < nfl) { tv = tgtp[g]; ov = outp[g]; }
                        tl[i * 4 + c] = tv;
                        ol[i * 4 + c] = ov;
                    }
                }
            }
        }
    }
    __syncthreads();

    const float* tw = tl + s_l * FPS;
    const float* ow = ol + s_l * FPS;

    // ---- moments: packed-f32 accumulation, 9 float2 FMAs per point ----
    float2 P0 = f2(0,0), P1 = f2(0,0), P2 = f2(0,0), P3 = f2(0,0);
    float2 P4 = f2(0,0), P5 = f2(0,0), P6 = f2(0,0), P7 = f2(0,0);
    float2 Q  = f2(0,0);

#define PA_ACC(t0, t1, t2, o0, o1, o2)          \
    P0 += f2(t0, t1);                           \
    P1 += f2(t2, o0);                           \
    P2 += f2(o1, o2);                           \
    P3 += f2(t0, t0) * f2(o0, o1);              \
    P4 += f2(t0, t1) * f2(o2, o0);              \
    P5 += f2(t1, t1) * f2(o1, o2);              \
    P6 += f2(t2, t2) * f2(o0, o1);              \
    P7 += f2(t2, t0) * f2(o2, t0);              \
    Q  += f2(t1, t2) * f2(t1, t2);

    #pragma unroll
    for (int k = 0; k < 8; ++k) {
        const int idx = 3 * (l16 + 16 * k);
        const float t0 = tw[idx + 0], t1 = tw[idx + 1], t2 = tw[idx + 2];
        const float o0 = ow[idx + 0], o1 = ow[idx + 1], o2 = ow[idx + 2];
        PA_ACC(t0, t1, t2, o0, o1, o2)
    }
    if (l16 < 5) {
        const int idx = 3 * (128 + l16);
        const float t0 = tw[idx + 0], t1 = tw[idx + 1], t2 = tw[idx + 2];
        const float o0 = ow[idx + 0], o1 = ow[idx + 1], o2 = ow[idx + 2];
        PA_ACC(t0, t1, t2, o0, o1, o2)
    }
#undef PA_ACC

    float red[16];
    red[0]  = P0.x; red[1]  = P0.y; red[2]  = P1.x; red[3]  = P1.y;
    red[4]  = P2.x; red[5]  = P2.y; red[6]  = P3.x; red[7]  = P3.y;
    red[8]  = P4.x; red[9]  = P4.y; red[10] = P5.x; red[11] = P5.y;
    red[12] = P6.x; red[13] = P6.y; red[14] = P7.x; red[15] = P7.y + Q.x + Q.y;

    // ---- 4-stage value-splitting butterfly within 16-lane group ----
    float v8[8];
    {
        const bool b = (lane & 1);
        #pragma unroll
        for (int m = 0; m < 8; ++m) {
            const float snd = b ? red[2 * m] : red[2 * m + 1];
            const float rcv = DPP_XOR1(snd);
            v8[m] = (b ? red[2 * m + 1] : red[2 * m]) + rcv;
        }
    }
    float v4_[4];
    {
        const bool b = ((lane >> 1) & 1);
        #pragma unroll
        for (int m = 0; m < 4; ++m) {
            const float snd = b ? v8[2 * m] : v8[2 * m + 1];
            const float rcv = DPP_XOR2(snd);
            v4_[m] = (b ? v8[2 * m + 1] : v8[2 * m]) + rcv;
        }
    }
    float v2_[2];
    {
        const bool b = ((lane >> 2) & 1);
        #pragma unroll
        for (int m = 0; m < 2; ++m) {
            const float snd = b ? v4_[2 * m] : v4_[2 * m + 1];
            const float rcv = __shfl_xor(snd, 4, 64);
            v2_[m] = (b ? v4_[2 * m + 1] : v4_[2 * m]) + rcv;
        }
    }
    float v1;
    {
        const bool b = ((lane >> 3) & 1);
        const float snd = b ? v2_[0] : v2_[1];
        const float rcv = __shfl_xor(snd, 8, 64);
        v1 = (b ? v2_[1] : v2_[0]) + rcv;
    }

    momT[s_l][l16] = v1;
    __syncthreads();

    // ---- solve: wave 0, lanes 0..15, one sample each ----
    if (wid == 0 && lane < SPB && (blockIdx.x * SPB + lane) < nsamp) {
        float m_[16];
        #pragma unroll
        for (int j = 0; j < 16; ++j) m_[j] = momT[lane][j];

        const float invK = 1.0f / (float)KPTS;
        const float mu1x = m_[0] * invK, mu1y = m_[1] * invK, mu1z = m_[2] * invK;
        const float mu2x = m_[3] * invK, mu2y = m_[4] * invK, mu2z = m_[5] * invK;

        const float Sxx = m_[6]  - m_[0] * m_[3] * invK;
        const float Sxy = m_[7]  - m_[0] * m_[4] * invK;
        const float Sxz = m_[8]  - m_[0] * m_[5] * invK;
        const float Syx = m_[9]  - m_[1] * m_[3] * invK;
        const float Syy = m_[10] - m_[1] * m_[4] * invK;
        const float Syz = m_[11] - m_[1] * m_[5] * invK;
        const float Szx = m_[12] - m_[2] * m_[3] * invK;
        const float Szy = m_[13] - m_[2] * m_[4] * invK;
        const float Szz = m_[14] - m_[2] * m_[5] * invK;
        const float var1 = m_[15] - (m_[0] * m_[0] + m_[1] * m_[1] + m_[2] * m_[2]) * invK;

        const float N00 = Sxx + Syy + Szz;
        const float N01 = Syz - Szy, N02 = Szx - Sxz, N03 = Sxy - Syx;
        const float N11 = Sxx - Syy - Szz, N12 = Sxy + Syx, N13 = Szx + Sxz;
        const float N22 = -Sxx + Syy - Szz, N23 = Syz + Szy;
        const float N33 = -Sxx - Syy + Szz;

        const float trKtK = Sxx * Sxx + Sxy * Sxy + Sxz * Sxz
                          + Syx * Syx + Syy * Syy + Syz * Syz
                          + Szx * Szx + Szy * Szy + Szz * Szz;
        const float c2 = -2.0f * trKtK;
        const float detK = det3(Sxx, Sxy, Sxz, Syx, Syy, Syz, Szx, Szy, Szz);
        const float c1 = -8.0f * detK;
        const float c0 =
              N00 * det3(N11, N12, N13, N12, N22, N23, N13, N23, N33)
            - N01 * det3(N01, N12, N13, N02, N22, N23, N03, N23, N33)
            + N02 * det3(N01, N11, N13, N02, N12, N23, N03, N13, N33)
            - N03 * det3(N01, N11, N12, N02, N12, N22, N03, N13, N23);

        float lam = sqrtf(fmaxf(3.0f * trKtK, 0.0f));
        #pragma unroll
        for (int it = 0; it < 10; ++it) {
            const float l2 = lam * lam;
            const float P  = (l2 + c2) * l2 + c1 * lam + c0;
            const float Pp = (4.0f * l2 + 2.0f * c2) * lam + c1;
            lam -= P / Pp;
        }

        const float M00 = N00 - lam, M11 = N11 - lam, M22 = N22 - lam, M33 = N33 - lam;
        const float a0 =  det3(M11, N12, N13, N12, M22, N23, N13, N23, M33);
        const float a1 = -det3(N01, N12, N13, N02, M22, N23, N03, N23, M33);
        const float a2 =  det3(N01, M11, N13, N02, N12, N23, N03, N13, M33);
        const float a3 = -det3(N01, M11, N12, N02, N12, M22, N03, N13, N23);
        const float b0 = -det3(N01, N02, N03, N12, M22, N23, N13, N23, M33);
        const float b1 =  det3(M00, N02, N03, N02, M22, N23, N03, N23, M33);
        const float b2 = -det3(M00, N01, N03, N02, N12, N23, N03, N13, M33);
        const float b3 =  det3(M00, N01, N02, N02, N12, M22, N03, N13, N23);
        const float na = a0 * a0 + a1 * a1 + a2 * a2 + a3 * a3;
        const float nb = b0 * b0 + b1 * b1 + b2 * b2 + b3 * b3;
        const bool pa_ = (na >= nb);
        float qw = pa_ ? a0 : b0;
        float qx = pa_ ? a1 : b1;
        float qy = pa_ ? a2 : b2;
        float qz = pa_ ? a3 : b3;
        const float qn = rsqrtf(fmaxf(qw * qw + qx * qx + qy * qy + qz * qz, 1e-30f));
        qw *= qn; qx *= qn; qy *= qn; qz *= qn;

        const float R00 = 1.0f - 2.0f * (qy * qy + qz * qz);
        const float R01 = 2.0f * (qx * qy - qw * qz);
        const float R02 = 2.0f * (qx * qz + qw * qy);
        const float R10 = 2.0f * (qx * qy + qw * qz);
        const float R11 = 1.0f - 2.0f * (qx * qx + qz * qz);
        const float R12 = 2.0f * (qy * qz - qw * qx);
        const float R20 = 2.0f * (qx * qz - qw * qy);
        const float R21 = 2.0f * (qy * qz + qw * qx);
        const float R22 = 1.0f - 2.0f * (qx * qx + qy * qy);

        const float trRK = R00 * Sxx + R01 * Syx + R02 * Szx
                         + R10 * Sxy + R11 * Syy + R12 * Szy
                         + R20 * Sxz + R21 * Syz + R22 * Szz;
        const float scale = trRK / var1;

        const float tx = mu2x - scale * (R00 * mu1x + R01 * mu1y + R02 * mu1z);
        const float ty = mu2y - scale * (R10 * mu1x + R11 * mu1y + R12 * mu1z);
        const float tz = mu2z - scale * (R20 * mu1x + R21 * mu1y + R22 * mu1z);

        prm[lane][0] = scale * R00; prm[lane][1] = scale * R01; prm[lane][2] = scale * R02;
        prm[lane][3] = scale * R10; prm[lane][4] = scale * R11; prm[lane][5] = scale * R12;
        prm[lane][6] = scale * R20; prm[lane][7] = scale * R21; prm[lane][8] = scale * R22;
        prm[lane][9] = tx; prm[lane][10] = ty; prm[lane][11] = tz;
    }
    __syncthreads();

    // ---- residuals: packed-f32 transform, from LDS image ----
    const float2 rA = f2(prm[s_l][0], prm[s_l][3]);   // (sR00, sR10)
    const float2 rB = f2(prm[s_l][1], prm[s_l][4]);   // (sR01, sR11)
    const float2 rC = f2(prm[s_l][2], prm[s_l][5]);   // (sR02, sR12)
    const float sR20 = prm[s_l][6], sR21 = prm[s_l][7], sR22 = prm[s_l][8];
    const float2 txy = f2(prm[s_l][9], prm[s_l][10]);
    const float tz = prm[s_l][11];

    float rsum = 0.0f;
#define PA_RES(t0, t1, t2, o0, o1, o2)                                     \
    {                                                                      \
        float2 axy = txy;                                                  \
        axy += rA * f2(t0, t0);                                            \
        axy += rB * f2(t1, t1);                                            \
        axy += rC * f2(t2, t2);                                            \
        const float az = fmaf(sR20, (t0), fmaf(sR21, (t1), fmaf(sR22, (t2), tz))); \
        const float2 dxy = f2(o0, o1) - axy;                               \
        const float dz = (o2) - az;                                        \
        const float ns = fmaf(dxy.x, dxy.x, fmaf(dxy.y, dxy.y, dz * dz));  \
        rsum += sqrtf(ns);                                                 \
    }
    #pragma unroll
    for (int k = 0; k < 8; ++k) {
        const int idx = 3 * (l16 + 16 * k);
        const float t0 = tw[idx + 0], t1 = tw[idx + 1], t2 = tw[idx + 2];
        const float o0 = ow[idx + 0], o1 = ow[idx + 1], o2 = ow[idx + 2];
        PA_RES(t0, t1, t2, o0, o1, o2)
    }
    if (l16 < 5) {
        const int idx = 3 * (128 + l16);
        const float t0 = tw[idx + 0], t1 = tw[idx + 1], t2 = tw[idx + 2];
        const float o0 = ow[idx + 0], o1 = ow[idx + 1], o2 = ow[idx + 2];
        PA_RES(t0, t1, t2, o0, o1, o2)
    }
#undef PA_RES

    rsum = valid ? rsum : 0.0f;

    rsum += DPP_XOR1(rsum);
    rsum += DPP_XOR2(rsum);
    rsum += __shfl_xor(rsum, 4, 64);
    rsum += __shfl_xor(rsum, 8, 64);

    if (l16 == 0) shs[s_l] = rsum;
    __syncthreads();
    if (tid == 0) {
        float b = 0.0f;
        #pragma unroll
        for (int i = 0; i < SPB; ++i) b += shs[i];
        block_sums[blockIdx.x] = b;
    }
}

// Deterministic final reduction: one block, fixed order, 4-way ILP.
__global__ __launch_bounds__(256) void pa_reduce_kernel(
    const float* __restrict__ block_sums, int n,
    float* __restrict__ out, float inv_total)
{
    __shared__ float sh[4];
    float a0 = 0.f, a1 = 0.f, a2 = 0.f, a3 = 0.f;
    for (int i = (int)threadIdx.x * 4; i < n; i += 1024) {
        if (i + 0 < n) a0 += block_sums[i + 0];
        if (i + 1 < n) a1 += block_sums[i + 1];
        if (i + 2 < n) a2 += block_sums[i + 2];
        if (i + 3 < n) a3 += block_sums[i + 3];
    }
    float v = (a0 + a1) + (a2 + a3);
    #pragma unroll
    for (int off = 32; off >= 1; off >>= 1) v += __shfl_xor(v, off, 64);
    const int lane = threadIdx.x & 63;
    const int wid  = threadIdx.x >> 6;
    if (lane == 0) sh[wid] = v;
    __syncthreads();
    if (threadIdx.x == 0) out[0] = (sh[0] + sh[1] + sh[2] + sh[3]) * inv_total;
}

extern "C" void kernel_launch(void* const* d_in, const int* in_sizes, int n_in,
                              void* d_out, int out_size, void* d_ws, size_t ws_size,
                              hipStream_t stream) {
    const float* outp = (const float*)d_in[0];   // "output"
    const float* tgtp = (const float*)d_in[1];   // "target"
    const int nsamp   = in_sizes[0] / FPS;
    const int nblocks = (nsamp + SPB - 1) / SPB;

    float* bsums = (float*)d_ws;

    pa_mpjpe_kernel<<<nblocks, 256, 0, stream>>>(outp, tgtp, bsums, nsamp);
    pa_reduce_kernel<<<1, 256, 0, stream>>>(
        bsums, nblocks, (float*)d_out,
        1.0f / ((float)nsamp * (float)KPTS));
}